// Round 1
// 487.938 us; speedup vs baseline: 1.1728x; 1.1728x over previous
//
#include <hip/hip_runtime.h>

// RNN_73813307949430: 4x LSTM(H=50,T=10,F=5) + Dense(50) + Dense(1,sigmoid), B=131072.
// Round 4: FULL 4-LAYER FUSION. One kernel carries a 32-row batch tile through all
// layers and timesteps. h-states live in LDS: buf[t] holds h^{l-1}_t (X input) and is
// overwritten in place with h^l_t (barrier separates MFMA reads from gate writes).
// Eliminates the 168MB-per-layer hbuf HBM round-trips (~1 GB), 3 launches, and all
// per-t global staging. MTILE=32 -> 46 KB LDS -> 3 blocks/CU (occupancy 20%->~37%).
//
// LDS buf per t: chunk(mt,kk,quad,rr) at u16 offset ((mt*2+kk)*4+quad)*128 + rr*8
// holds h[row=mt*16+rr][unit=kk*32+quad*8+j]. MFMA A-frag for (mt,kt): lane(np,quad)
// reads 16B at mt*1024+kt*512+quad*128+np*8 -> consecutive per lane = conflict-free.
// Weights Wpp unchanged from round 3b (k 0..63 = X/h^{l-1}, k 64..127 = recurrent).

typedef __attribute__((ext_vector_type(8))) short short8;
typedef __attribute__((ext_vector_type(4))) float floatx4;
typedef __attribute__((ext_vector_type(2))) float float2v;
typedef unsigned short u16;
typedef unsigned int u32;

constexpr int H_ = 50, T_ = 10, F_ = 5;
constexpr int MTILE = 32;   // batch rows per block
constexpr int BLKT = 256;   // 4 waves
constexpr float LOG2E = 1.4426950408889634f;

__device__ __forceinline__ float rcp_(float x) { return __builtin_amdgcn_rcpf(x); }
__device__ __forceinline__ float exp2_(float x) { return __builtin_amdgcn_exp2f(x); }
__device__ __forceinline__ float sig_nat(float x) {
  return rcp_(1.0f + exp2_(-LOG2E * x));
}

__device__ __forceinline__ u16 f2bf(float f) {
  union { float f; unsigned u; } v; v.f = f;
  unsigned r = v.u + 0x7FFFu + ((v.u >> 16) & 1u);  // RNE
  return (u16)(r >> 16);
}
__device__ __forceinline__ float bf2f(u16 s) {
  union { unsigned u; float f; } v; v.u = ((unsigned)s) << 16;
  return v.f;
}
__device__ __forceinline__ unsigned pk_bf16(float a, float b) {
  return (unsigned)f2bf(a) | ((unsigned)f2bf(b) << 16);
}

// ---- prep: swizzle weights into B-fragment order with activation prescale ----
// Wpp[layer][kt][gate][wave][lane][8]; B[k=(lane>>4)*8+j][n=lane&15].
// Gates i,f,o scaled by -log2e (sig = rcp(1+exp2(z))); gate g by +2*log2e
// (tanh = 1-2*rcp(1+exp2(z))). Bias scaled identically.
__global__ void prep_kernel(
    const float* W1, const float* U1, const float* b1, const float* W2,
    const float* U2, const float* b2, const float* W3, const float* U3,
    const float* b3, const float* W4, const float* U4, const float* b4,
    const float* Wd1, const float* bd1, const float* Wd2, const float* bd2,
    u16* Wpp, float* biasP, float* vdense) {
  int idx = blockIdx.x * blockDim.x + threadIdx.x;
  const float* Wt[4] = {W1, W2, W3, W4};
  const float* Ut[4] = {U1, U2, U3, U4};
  const float* bt[4] = {b1, b2, b3, b4};
  const int fin[4] = {F_, H_, H_, H_};
  if (idx < 4 * 32768) {
    int l = idx >> 15, r = idx & 32767;
    int j = r & 7, lane = (r >> 3) & 63, w = (r >> 9) & 3, gI = (r >> 11) & 3,
        kt = r >> 13;
    int row = kt * 32 + (lane >> 4) * 8 + j;  // K position (0..127)
    int u = w * 16 + (lane & 15);             // unit (0..63)
    float val = 0.0f;
    if (u < H_) {
      if (row < 64) {
        if (row < fin[l]) val = Wt[l][row * 200 + gI * H_ + u];
      } else {
        int rr = row - 64;
        if (rr < H_) val = Ut[l][rr * 200 + gI * H_ + u];
      }
    }
    val *= (gI == 2) ? (2.0f * LOG2E) : (-LOG2E);
    Wpp[idx] = f2bf(val);
  } else if (idx < 4 * 32768 + 1024) {
    int r = idx - 4 * 32768;
    int l = r >> 8, q = r & 255, gI = q >> 6, u = q & 63;
    float val = (u < H_) ? bt[l][gI * H_ + u] : 0.0f;
    biasP[r] = val * ((gI == 2) ? (2.0f * LOG2E) : (-LOG2E));
  } else if (idx < 4 * 32768 + 1024 + 51) {
    int u = idx - (4 * 32768 + 1024);
    if (u < H_) {  // v = Wd1 @ Wd2 (Dense(50) linear -> collapse)
      float s = 0.0f;
      for (int n = 0; n < H_; ++n) s += Wd1[u * H_ + n] * Wd2[n];
      vdense[u] = s;
    } else {
      float s = bd2[0];
      for (int n = 0; n < H_; ++n) s += bd1[n] * Wd2[n];
      vdense[50] = s;
    }
  }
}

// ---- fully fused 4-layer LSTM + dense head ----
__global__ __launch_bounds__(BLKT, 3) void lstm_fused(
    const float* __restrict__ x0, const u16* __restrict__ Wpp,
    const float* __restrict__ biasP, const float* __restrict__ vdense,
    float* __restrict__ out) {
  // buf[t]: 2048 u16 (4 KB). In-place: holds h^{l-1}_t as X input, overwritten
  // with h^l_t after the per-step barrier.
  __shared__ __align__(16) u16 buf[T_ * 2048];  // 40 KB
  __shared__ __align__(16) u16 xb[T_ * 256];    // 5 KB: layer-1 X, (t,row,j) j=f pad 8
  __shared__ __align__(16) u16 zc[8];           // zero chunk for layer-1 quads 1..3

  const int tid = threadIdx.x;
  const int w = tid >> 6, lane = tid & 63;
  const int np = lane & 15, quad = lane >> 4;
  const int b0 = blockIdx.x * MTILE;
  const int u = w * 16 + np;

  // zero xb (j=5..7 stay zero) and zc
  for (int i = tid; i < T_ * 128; i += BLKT) ((u32*)xb)[i] = 0;
  if (tid < 4) ((u32*)zc)[tid] = 0;
  __syncthreads();

  // stage ALL timesteps of layer-1 input once (coalesced: 50 contiguous f32/row)
  for (int e = tid; e < MTILE * 50; e += BLKT) {
    int row = e / 50, q = e - row * 50;
    int t = q / 5, f = q - t * 5;
    xb[t * 256 + row * 8 + f] = f2bf(x0[(size_t)(b0 + row) * 50 + q]);
  }
  __syncthreads();

  // A-frag read base: chunk(mt,kt,quad,rr=np) -> mt*1024 + kt*512 + quad*128 + np*8
  const int rbase = quad * 128 + np * 8;
  // h-write base: unit u -> kk=u>>5=w>>1, qk=((w&1)*2+(np>>3)), j=np&7; rows quad*4+2p
  const int cb0 = (w >> 1) * 512 + ((w & 1) * 2 + (np >> 3)) * 128 + quad * 32 + (np & 7);

  float2v cst[4];  // c state pairs: [mt*2+p], rows mt*16+quad*4+{2p,2p+1}, unit u

#pragma unroll 1
  for (int l = 0; l < 4; ++l) {
    // per-layer weight fragments from L2 (prescaled), 64 VGPRs
    const u16* wp = Wpp + l * 32768;
    short8 bfr[4][4];
#pragma unroll
    for (int kt = 0; kt < 4; ++kt)
#pragma unroll
      for (int g = 0; g < 4; ++g)
        bfr[kt][g] = *(const short8*)&wp[(((kt * 4 + g) * 4 + w) * 64 + lane) * 8];
    float bv[4];
#pragma unroll
    for (int g = 0; g < 4; ++g) bv[g] = biasP[l * 256 + g * 64 + u];
#pragma unroll
    for (int i = 0; i < 4; ++i) cst[i] = float2v{0.0f, 0.0f};

#pragma unroll 1
    for (int t = 0; t < T_; ++t) {
      u16* bt = &buf[t * 2048];
      const u16* bp = &buf[(t == 0 ? 0 : (t - 1)) * 2048];

      floatx4 acc[2][4];
#pragma unroll
      for (int mt = 0; mt < 2; ++mt)
#pragma unroll
        for (int g = 0; g < 4; ++g)
          acc[mt][g] = floatx4{bv[g], bv[g], bv[g], bv[g]};

      if (l == 0) {  // X = staged input, K=0..31 only (F=5, rest zero weights)
#pragma unroll
        for (int mt = 0; mt < 2; ++mt) {
          const u16* ap = (quad == 0) ? &xb[t * 256 + (mt * 16 + np) * 8] : zc;
          short8 af = *(const short8*)ap;
#pragma unroll
          for (int g = 0; g < 4; ++g)
            acc[mt][g] = __builtin_amdgcn_mfma_f32_16x16x32_bf16(
                af, bfr[0][g], acc[mt][g], 0, 0, 0);
        }
      } else {  // X = h^{l-1}_t in buf[t]
#pragma unroll
        for (int mt = 0; mt < 2; ++mt) {
          short8 a0 = *(const short8*)&bt[mt * 1024 + rbase];
          short8 a1 = *(const short8*)&bt[mt * 1024 + 512 + rbase];
#pragma unroll
          for (int g = 0; g < 4; ++g) {
            acc[mt][g] = __builtin_amdgcn_mfma_f32_16x16x32_bf16(
                a0, bfr[0][g], acc[mt][g], 0, 0, 0);
            acc[mt][g] = __builtin_amdgcn_mfma_f32_16x16x32_bf16(
                a1, bfr[1][g], acc[mt][g], 0, 0, 0);
          }
        }
      }
      if (t > 0) {  // recurrent H = h^l_{t-1} in buf[t-1]; h_{-1}=0 -> skip at t=0
#pragma unroll
        for (int mt = 0; mt < 2; ++mt) {
          short8 h0 = *(const short8*)&bp[mt * 1024 + rbase];
          short8 h1 = *(const short8*)&bp[mt * 1024 + 512 + rbase];
#pragma unroll
          for (int g = 0; g < 4; ++g) {
            acc[mt][g] = __builtin_amdgcn_mfma_f32_16x16x32_bf16(
                h0, bfr[2][g], acc[mt][g], 0, 0, 0);
            acc[mt][g] = __builtin_amdgcn_mfma_f32_16x16x32_bf16(
                h1, bfr[3][g], acc[mt][g], 0, 0, 0);
          }
        }
      }
      // l==0 reads only xb & buf[t-1]; writes to buf[t] are disjoint -> no barrier.
      // l>0 reads buf[t] as X -> must drain all waves' reads before overwrite.
      if (l > 0) __syncthreads();

      // ---- gates: pairwise (v_pk_f32), shared reciprocals, prescaled z ----
#pragma unroll
      for (int mt = 0; mt < 2; ++mt) {
#pragma unroll
        for (int p = 0; p < 2; ++p) {
          float2v di = {exp2_(acc[mt][0][2 * p]), exp2_(acc[mt][0][2 * p + 1])};
          float2v df = {exp2_(acc[mt][1][2 * p]), exp2_(acc[mt][1][2 * p + 1])};
          float2v dg = {exp2_(acc[mt][2][2 * p]), exp2_(acc[mt][2][2 * p + 1])};
          float2v do_ = {exp2_(acc[mt][3][2 * p]), exp2_(acc[mt][3][2 * p + 1])};
          di += 1.0f; df += 1.0f; dg += 1.0f; do_ += 1.0f;
          float2v m1 = di * df, m2 = do_ * dg;
          float2v P = m1 * m2;                       // di*df*do*dg
          float Rs = rcp_(P.x * P.y);                // one rcp for 8 factors
          float2v R = {Rs * P.y, Rs * P.x};
          float2v i_ = (df * m2) * R;                // = 1/di
          float2v f_ = (di * m2) * R;                // = 1/df
          float2v o_ = (m1 * dg) * R;                // = 1/do
          float2v g_ = 1.0f - 2.0f * ((m1 * do_) * R);  // = 1-2/dg
          float2v cn = f_ * cst[mt * 2 + p] + i_ * g_;
          cst[mt * 2 + p] = cn;
          float2v s = cn * (2.0f * LOG2E);
          float2v dc = {exp2_(s.x), exp2_(s.y)};
          dc += 1.0f;
          float Rc = rcp_(dc.x * dc.y);
          float2v tc = 1.0f - 2.0f * float2v{Rc * dc.y, Rc * dc.x};
          float2v h = o_ * tc;
          unsigned pk = pk_bf16(h.x, h.y);
          int a0 = cb0 + mt * 1024 + p * 16;
          bt[a0] = (u16)pk;
          bt[a0 + 8] = (u16)(pk >> 16);
        }
      }
      __syncthreads();  // h^l_t visible for next step / next layer
    }
  }

  // ---- dense head: out = sigmoid(h^4_9 . (Wd1@Wd2) + beta) ----
  if (tid < MTILE) {
    int mt = tid >> 4, rr = tid & 15;
    const u16* b9 = &buf[9 * 2048];
    float s = vdense[50];
    for (int k = 0; k < H_; ++k) {
      int kk = k >> 5, qd = (k & 31) >> 3, j = k & 7;
      s += bf2f(b9[mt * 1024 + kk * 512 + qd * 128 + rr * 8 + j]) * vdense[k];
    }
    out[b0 + tid] = sig_nat(s);
  }
}

extern "C" void kernel_launch(void* const* d_in, const int* in_sizes, int n_in,
                              void* d_out, int out_size, void* d_ws,
                              size_t ws_size, hipStream_t stream) {
  const float* x = (const float*)d_in[0];
  const float* W1 = (const float*)d_in[1];
  const float* U1 = (const float*)d_in[2];
  const float* b1 = (const float*)d_in[3];
  const float* W2 = (const float*)d_in[4];
  const float* U2 = (const float*)d_in[5];
  const float* b2 = (const float*)d_in[6];
  const float* W3 = (const float*)d_in[7];
  const float* U3 = (const float*)d_in[8];
  const float* b3 = (const float*)d_in[9];
  const float* W4 = (const float*)d_in[10];
  const float* U4 = (const float*)d_in[11];
  const float* b4 = (const float*)d_in[12];
  const float* Wd1 = (const float*)d_in[13];
  const float* bd1 = (const float*)d_in[14];
  const float* Wd2 = (const float*)d_in[15];
  const float* bd2 = (const float*)d_in[16];

  const int Bn = in_sizes[0] / (T_ * F_);  // 131072
  const int nblk = Bn / MTILE;             // 4096
  char* ws = (char*)d_ws;
  u16* Wpp = (u16*)ws;                          // 4 x 32768 bf16 = 256 KB
  float* biasP = (float*)(ws + 262144);         // 4 x 256 f32
  float* vdense = (float*)(ws + 262144 + 4096); // 51 f32
  float* out = (float*)d_out;

  prep_kernel<<<(4 * 32768 + 1024 + 51 + 255) / 256, 256, 0, stream>>>(
      W1, U1, b1, W2, U2, b2, W3, U3, b3, W4, U4, b4, Wd1, bd1, Wd2, bd2, Wpp,
      biasP, vdense);

  lstm_fused<<<dim3(nblk), dim3(BLKT), 0, stream>>>(x, Wpp, biasP, vdense, out);
}